// Round 4
// baseline (800.146 us; speedup 1.0000x reference)
//
#include <hip/hip_runtime.h>
#include <hip/hip_bf16.h>

// Problem constants
#define B_ 256
#define T_ 96
#define F_ 368
#define H_ 368
#define G3_ 1104          // 3*H
#define NC_ 29            // fine classes
#define BT_ (B_*T_)       // 24576
#define HB_ (H_*B_)       // 94208, one time-slice of temporal [u][b]

// GRU geometry
#define NSL 8             // unit slices
#define NU 46             // units per slice (8*46 = 368)
#define NCOL 138          // cols per slice = 3*NU
#define ROWS 8            // batch rows per group
#define WQCOLS 1152       // (legacy name, used for split-B overlay sizing)

// MFMA-GRU geometry: per slice N=138 -> 9 tiles of 16 (cols 138..143 pad),
// K=368 -> 12 k-tiles of 32 (k 368..383 pad). Wq2 frag store:
// [us 8][nt 9][kt 12][plane 2][lane 64][e 8] u16 = 1,769,472 B.
#define WQ2_U16 (8*9*12*2*64*8)

// h-word sentinel: hi half 0x7FC0 = bf16 NaN; finite h (|h|<=1) can never
// produce it, so a non-sentinel read proves the producer's store landed.
#define SENT 0x7FC07FC0u

#define F4C(v, i) ((i)==0?(v).x:((i)==1?(v).y:((i)==2?(v).z:(v).w)))

typedef __attribute__((ext_vector_type(8))) short bhalf8;   // 8 bf16 = 4 VGPR
typedef __attribute__((ext_vector_type(4))) float f32x4;

// ---- bf16 split helpers (bit-level RNE, no header dependence) -------------
__device__ __forceinline__ unsigned short f2bf(float x) {
    unsigned u = __float_as_uint(x);
    u += 0x7fffu + ((u >> 16) & 1u);
    return (unsigned short)(u >> 16);
}
__device__ __forceinline__ float bf2f(unsigned short b) {
    return __uint_as_float(((unsigned)b) << 16);
}

// async global->LDS, 16B per lane; lds base must be wave-uniform
__device__ __forceinline__ void gll16(const void* g, void* l) {
    __builtin_amdgcn_global_load_lds(
        (const __attribute__((address_space(1))) void*)g,
        (__attribute__((address_space(3))) void*)l, 16, 0, 0);
}

// ---- fence-free cross-XCD exchange primitives ----------------------------
__device__ __forceinline__ unsigned int bload_u(const unsigned int* p) {
    return __hip_atomic_load(p, __ATOMIC_RELAXED, __HIP_MEMORY_SCOPE_AGENT);
}
__device__ __forceinline__ void bstore_u(unsigned int* p, unsigned int v) {
    __hip_atomic_store(p, v, __ATOMIC_RELAXED, __HIP_MEMORY_SCOPE_AGENT);
}

// LDS-only barrier: orders ds ops across the WG WITHOUT draining vmcnt, so
// in-flight agent-scope h stores keep flying across step boundaries.
__device__ __forceinline__ void barrier_lds() {
    asm volatile("s_waitcnt lgkmcnt(0)\ns_barrier" ::: "memory");
}

// ---------------------------------------------------------------------------
// K0: pack Wh (1104x368) into bf16 hi/lo B-fragments Wq2.
// ---------------------------------------------------------------------------
__global__ __launch_bounds__(256) void k_prep_wq2(const float* __restrict__ Wh,
                                                  unsigned short* __restrict__ Wq2) {
    const int idx = blockIdx.x*256 + threadIdx.x;   // < 110592 (432 blocks exact)
    const int l = idx & 63;
    const int p = (idx >> 6) & 1;
    int q = idx >> 7;
    const int kt = q % 12; q /= 12;
    const int nt = q % 9;
    const int us = q / 9;
    const int col = nt*16 + (l & 15);
    const int k0 = kt*32 + (l >> 4)*8;              // multiple of 8; 368%8==0
    float v[8];
    #pragma unroll
    for (int e = 0; e < 8; ++e) v[e] = 0.f;
    if (col < NCOL && k0 < H_) {
        const int g = col / NU, uu = col - g*NU;
        const int grow = g*H_ + us*NU + uu;         // < 1104
        const float4 f0 = *reinterpret_cast<const float4*>(Wh + (size_t)grow*H_ + k0);
        const float4 f1 = *reinterpret_cast<const float4*>(Wh + (size_t)grow*H_ + k0 + 4);
        v[0]=f0.x; v[1]=f0.y; v[2]=f0.z; v[3]=f0.w;
        v[4]=f1.x; v[5]=f1.y; v[6]=f1.z; v[7]=f1.w;
    }
    unsigned int o[4];
    #pragma unroll
    for (int e = 0; e < 4; ++e) {
        const unsigned short h0 = f2bf(v[2*e]), h1 = f2bf(v[2*e+1]);
        const unsigned short w0 = p ? f2bf(v[2*e]   - bf2f(h0)) : h0;
        const unsigned short w1 = p ? f2bf(v[2*e+1] - bf2f(h1)) : h1;
        o[e] = (unsigned)w0 | ((unsigned)w1 << 16);
    }
    uint4* dst = reinterpret_cast<uint4*>(Wq2 + (size_t)idx*8);
    *dst = make_uint4(o[0], o[1], o[2], o[3]);
}

// ---------------------------------------------------------------------------
// K0b: pack head weights Wcat[u][32]
// ---------------------------------------------------------------------------
__global__ __launch_bounds__(256) void k_prep_wcat(const float* __restrict__ Wc,
                                                   const float* __restrict__ Wf,
                                                   float* __restrict__ Wcat) {
    const int idx = blockIdx.x*256 + threadIdx.x;   // < 368*32 = 11776
    const int u = idx >> 5, c = idx & 31;
    float v = 0.f;
    if (c < 2) v = Wc[c*H_ + u];
    else if (c < 31) v = Wf[(c-2)*H_ + u];
    Wcat[idx] = v;
}

// ---------------------------------------------------------------------------
// K0f: fill the h-exchange buffer with the sentinel (re-poison each launch).
// 8832*256*4 u32 == 96*368*256 exactly.
// ---------------------------------------------------------------------------
__global__ __launch_bounds__(256) void k_fill_sent(unsigned int* __restrict__ p) {
    const int idx = blockIdx.x*256 + threadIdx.x;
    reinterpret_cast<uint4*>(p)[idx] = make_uint4(SENT, SENT, SENT, SENT);
}

// ---------------------------------------------------------------------------
// K0d: split features into hi/lo bf16 planes (Markidis split).
// ---------------------------------------------------------------------------
__global__ __launch_bounds__(256) void k_split_a(const float* __restrict__ src,
                                                 unsigned short* __restrict__ Ah,
                                                 unsigned short* __restrict__ Al) {
    const int idx = blockIdx.x*256 + threadIdx.x;
    const float4 v = reinterpret_cast<const float4*>(src)[idx];
    ushort4 h, lo;
    h.x = f2bf(v.x); lo.x = f2bf(v.x - bf2f(h.x));
    h.y = f2bf(v.y); lo.y = f2bf(v.y - bf2f(h.y));
    h.z = f2bf(v.z); lo.z = f2bf(v.z - bf2f(h.z));
    h.w = f2bf(v.w); lo.w = f2bf(v.w - bf2f(h.w));
    reinterpret_cast<ushort4*>(Ah)[idx] = h;
    reinterpret_cast<ushort4*>(Al)[idx] = lo;
}

// K0e: split Wi (1104x368) into hi/lo bf16, zero-padded to 1152 N-rows.
__global__ __launch_bounds__(256) void k_split_b(const float* __restrict__ Wi,
                                                 unsigned short* __restrict__ Bh,
                                                 unsigned short* __restrict__ Bl) {
    const int idx = blockIdx.x*256 + threadIdx.x;
    const float x = (idx < G3_*F_) ? Wi[idx] : 0.f;
    const unsigned short h = f2bf(x);
    Bh[idx] = h;
    Bl[idx] = f2bf(x - bf2f(h));
}

// ---------------------------------------------------------------------------
// K1: xproj GEMM via split-bf16 MFMA (proven round-1 kernel, unchanged).
// ---------------------------------------------------------------------------
__global__ __launch_bounds__(256) void k_xproj_mfma(
        const unsigned short* __restrict__ Ah, const unsigned short* __restrict__ Al,
        const unsigned short* __restrict__ Bh, const unsigned short* __restrict__ Bl,
        const float* __restrict__ bias, float* __restrict__ C)
{
    __shared__ unsigned short sAh[128*32], sAl[128*32], sBh[128*32], sBl[128*32];
    const int tid = threadIdx.x;
    const int w   = tid >> 6, l = tid & 63;
    const int gm0 = blockIdx.y * 128, gn0 = blockIdx.x * 128;

    const int srow = tid >> 2;                       // 0..63
    const int cg   = (tid & 3) ^ ((tid >> 3) & 3);   // source k-chunk (0..3)
    const size_t aoff0 = (size_t)(gm0 + srow)      * F_ + cg * 8;
    const size_t aoff1 = (size_t)(gm0 + srow + 64) * F_ + cg * 8;
    const size_t boff0 = (size_t)(gn0 + srow)      * F_ + cg * 8;
    const size_t boff1 = (size_t)(gn0 + srow + 64) * F_ + cg * 8;
    const int lb0 = w * 1024, lb1 = 4096 + w * 1024; // wave-uniform LDS bases

    const int lr = l & 15, lk = l >> 4;
    const int cswz = (lk ^ ((lr >> 1) & 3)) * 16;
    const int wr = w >> 1, wc = w & 1;
    int offA[4], offB[4];
    #pragma unroll
    for (int f = 0; f < 4; ++f) {
        offA[f] = (wr*64 + f*16 + lr) * 64 + cswz;
        offB[f] = (wc*64 + f*16 + lr) * 64 + cswz;
    }

    f32x4 acc[4][4];
    #pragma unroll
    for (int i = 0; i < 4; ++i)
        #pragma unroll
        for (int j = 0; j < 4; ++j) acc[i][j] = f32x4{0.f,0.f,0.f,0.f};

    auto stage = [&](int kt) {
        const size_t ko = (size_t)kt * 32;
        gll16(Ah + aoff0 + ko, (char*)sAh + lb0);
        gll16(Ah + aoff1 + ko, (char*)sAh + lb1);
        gll16(Al + aoff0 + ko, (char*)sAl + lb0);
        gll16(Al + aoff1 + ko, (char*)sAl + lb1);
        gll16(Bh + boff0 + ko, (char*)sBh + lb0);
        gll16(Bh + boff1 + ko, (char*)sBh + lb1);
        gll16(Bl + boff0 + ko, (char*)sBl + lb0);
        gll16(Bl + boff1 + ko, (char*)sBl + lb1);
    };

    stage(0);
    for (int kt = 0; kt < 12; ++kt) {
        __syncthreads();
        if (kt == 11) {
            if (cg >= 2) {
                const f32x4 z = f32x4{0.f,0.f,0.f,0.f};
                *reinterpret_cast<f32x4*>((char*)sAh + tid*16)        = z;
                *reinterpret_cast<f32x4*>((char*)sAh + tid*16 + 4096) = z;
                *reinterpret_cast<f32x4*>((char*)sAl + tid*16)        = z;
                *reinterpret_cast<f32x4*>((char*)sAl + tid*16 + 4096) = z;
                *reinterpret_cast<f32x4*>((char*)sBh + tid*16)        = z;
                *reinterpret_cast<f32x4*>((char*)sBh + tid*16 + 4096) = z;
                *reinterpret_cast<f32x4*>((char*)sBl + tid*16)        = z;
                *reinterpret_cast<f32x4*>((char*)sBl + tid*16 + 4096) = z;
            }
            __syncthreads();
        }
        bhalf8 fAh[4], fAl[4], fBh[4], fBl[4];
        #pragma unroll
        for (int f = 0; f < 4; ++f) {
            fAh[f] = *reinterpret_cast<const bhalf8*>((const char*)sAh + offA[f]);
            fAl[f] = *reinterpret_cast<const bhalf8*>((const char*)sAl + offA[f]);
            fBh[f] = *reinterpret_cast<const bhalf8*>((const char*)sBh + offB[f]);
            fBl[f] = *reinterpret_cast<const bhalf8*>((const char*)sBl + offB[f]);
        }
        __syncthreads();
        if (kt < 11) stage(kt + 1);
        #pragma unroll
        for (int i = 0; i < 4; ++i)
            #pragma unroll
            for (int j = 0; j < 4; ++j) {
                acc[i][j] = __builtin_amdgcn_mfma_f32_16x16x32_bf16(fAh[i], fBh[j], acc[i][j], 0, 0, 0);
                acc[i][j] = __builtin_amdgcn_mfma_f32_16x16x32_bf16(fAh[i], fBl[j], acc[i][j], 0, 0, 0);
                acc[i][j] = __builtin_amdgcn_mfma_f32_16x16x32_bf16(fAl[i], fBh[j], acc[i][j], 0, 0, 0);
            }
    }

    #pragma unroll
    for (int j = 0; j < 4; ++j) {
        const int gcol = gn0 + wc*64 + j*16 + lr;
        if (gcol < G3_) {
            const float bv = bias[gcol];
            #pragma unroll
            for (int i = 0; i < 4; ++i) {
                const int grow = gm0 + wr*64 + i*16 + lk*4;
                float* cp = C + (size_t)grow * G3_ + gcol;
                #pragma unroll
                for (int q = 0; q < 4; ++q)
                    cp[(size_t)q * G3_] = acc[i][j][q] + bv;
            }
        }
    }
}

// ---------------------------------------------------------------------------
// K2 v11: PERSISTENT MFMA GRU, sentinel-tagged exchange (no flags, no drain).
// Changes vs v10 (arithmetic bit-identical):
//  - h2 is pre-filled with SENT; consumers poll the DATA words directly and
//    exit when non-sentinel. Each 4B relaxed agent store is single-copy
//    atomic, so every word self-validates: the flag store, the flag poll
//    trip, and the producer-side vmcnt-drain release are all deleted.
//    Cross-WG exchange collapses from 4 serial coherence-point trips to ~1.
//  - all per-step barriers are raw {s_waitcnt lgkmcnt(0); s_barrier}: LDS
//    ordering preserved, in-flight h stores NOT drained at step boundaries.
// ---------------------------------------------------------------------------
__global__ __launch_bounds__(512, 2) void k_gru_all(const float* __restrict__ xproj,
                                                    const unsigned short* __restrict__ Wq2,
                                                    const float* __restrict__ bh,
                                                    unsigned int* __restrict__ h2) {
    __shared__ unsigned short sAh[48*16*8];     // [k-chunk][row16][e8], 12288 B
    __shared__ unsigned short sAl[48*16*8];     // 12288 B
    __shared__ float part2[4][144][9];          // [wk][col][row+pad], 20736 B
    const int tid = threadIdx.x;
    const int us  = blockIdx.x & 7;             // this WG's slice
    const int bg  = blockIdx.x >> 3;            // 0..31
    const int b0  = bg * ROWS;
    const int w   = tid >> 6;                   // wave 0..7
    const int l   = tid & 63;
    const int wk  = w >> 1;                     // K quarter (3 k-tiles)
    const int wn  = w & 1;                      // N half: tiles wn*4..wn*4+4
    const int nt0 = wn * 4;

    // zero-init LDS: A pad rows/chunks stay 0 forever; part2 zero for t=0
    for (int s = tid; s < 48*16*8; s += 512) { sAh[s] = 0; sAl[s] = 0; }
    for (int s = tid; s < 4*144*9; s += 512) (&part2[0][0][0])[s] = 0.f;

    // preload static B fragments: 5 tiles x 3 k-tiles x 2 planes = 120 VGPR
    bhalf8 bB[5][3][2];
    #pragma unroll
    for (int ti = 0; ti < 5; ++ti)
        #pragma unroll
        for (int kti = 0; kti < 3; ++kti)
            #pragma unroll
            for (int p = 0; p < 2; ++p)
                bB[ti][kti][p] = *reinterpret_cast<const bhalf8*>(
                    Wq2 + ((((size_t)(us*9 + nt0 + ti)*12 + (wk*3 + kti))*2 + p)*64 + l)*8);

    // gate-phase constants (one item per thread, tid < 368)
    const bool gact = tid < ROWS*NU;
    const int u1 = tid % NU, r1 = tid / NU;
    const int ug1 = us*NU + u1;
    float bh1r = 0.f, bh1z = 0.f, bh1n = 0.f;
    if (gact) { bh1r = bh[ug1]; bh1z = bh[H_+ug1]; bh1n = bh[2*H_+ug1]; }

    // staging geometry for this wave's slice (wave w stages slice w):
    // sl = l + ii*64, active sl<368; u = 46w + (sl>>3), r = sl&7
    int goff[6], aoff[6]; bool sact[6];
    #pragma unroll
    for (int ii = 0; ii < 6; ++ii) {
        const int sl = l + ii*64;
        sact[ii] = sl < NSL*NU;
        const int u = NU*w + ((sl < NSL*NU) ? (sl >> 3) : 0);
        const int r = sl & 7;
        goff[ii] = u*B_ + b0 + r;
        aoff[ii] = ((u >> 3)*16 + r)*8 + (u & 7);
    }

    // per-lane A-frag LDS byte offset within a k-tile block (1024 B / k-tile)
    const int aoffb = (l >> 4)*256 + (l & 15)*16;

    __syncthreads();

    for (int t = 0; t < T_; ++t) {
        unsigned int* hout = h2 + (size_t)t*HB_;

        // prefetch gate operands (independent of h; hides under poll)
        float xg10 = 0.f, xg11 = 0.f, xg12 = 0.f;
        if (gact) {
            const float* xr1 = xproj + ((size_t)(b0 + r1)*T_ + t)*G3_;
            xg10 = xr1[ug1]; xg11 = xr1[H_+ug1]; xg12 = xr1[2*H_+ug1];
        }

        if (t > 0) {
            // poll-load slice w of h(t-1): data words ARE the flags.
            const unsigned int* hin = h2 + (size_t)(t - 1)*HB_;
            unsigned int v[6];
            bool ok;
            do {
                unsigned bad = 0u;
                #pragma unroll
                for (int ii = 0; ii < 6; ++ii) {
                    v[ii] = 0u;
                    if (sact[ii]) {
                        v[ii] = bload_u(hin + goff[ii]);
                        bad |= (v[ii] == SENT) ? 1u : 0u;
                    }
                }
                ok = !__any(bad != 0u);
            } while (!ok);
            #pragma unroll
            for (int ii = 0; ii < 6; ++ii) {
                if (sact[ii]) {
                    sAh[aoff[ii]] = (unsigned short)(v[ii] & 0xffffu);
                    sAl[aoff[ii]] = (unsigned short)(v[ii] >> 16);
                }
            }
            barrier_lds();
            // MFMA: 3 k-tiles x 5 n-tiles x 3 split terms = 45 MFMAs/wave
            f32x4 acc[5];
            #pragma unroll
            for (int ti = 0; ti < 5; ++ti) acc[ti] = f32x4{0.f,0.f,0.f,0.f};
            #pragma unroll
            for (int kti = 0; kti < 3; ++kti) {
                const int kt = wk*3 + kti;
                const bhalf8 fh = *reinterpret_cast<const bhalf8*>((const char*)sAh + kt*1024 + aoffb);
                const bhalf8 fl = *reinterpret_cast<const bhalf8*>((const char*)sAl + kt*1024 + aoffb);
                #pragma unroll
                for (int ti = 0; ti < 5; ++ti) {
                    acc[ti] = __builtin_amdgcn_mfma_f32_16x16x32_bf16(fh, bB[ti][kti][0], acc[ti], 0, 0, 0);
                    acc[ti] = __builtin_amdgcn_mfma_f32_16x16x32_bf16(fh, bB[ti][kti][1], acc[ti], 0, 0, 0);
                    acc[ti] = __builtin_amdgcn_mfma_f32_16x16x32_bf16(fl, bB[ti][kti][0], acc[ti], 0, 0, 0);
                }
            }
            // C frags -> per-wk partials (padded, conflict-free).
            // C layout: col=lane&15, row=(lane>>4)*4+reg; rows 0..7 in lanes 0..31.
            if (l < 32) {
                #pragma unroll
                for (int ti = 0; ti < 5; ++ti) {
                    const int col = (nt0 + ti)*16 + (l & 15);
                    float* pp = &part2[wk][col][(l >> 4)*4];
                    pp[0] = acc[ti][0]; pp[1] = acc[ti][1];
                    pp[2] = acc[ti][2]; pp[3] = acc[ti][3];
                }
            }
        }
        barrier_lds();

        // fused gates: one (unit,row) per thread
        if (gact) {
            float s0 = 0.f, s1 = 0.f, s2 = 0.f;
            #pragma unroll
            for (int q2 = 0; q2 < 4; ++q2) {
                s0 += part2[q2][u1][r1];
                s1 += part2[q2][NU + u1][r1];
                s2 += part2[q2][2*NU + u1][r1];
            }
            const float rg = 1.f/(1.f + expf(-(xg10 + s0 + bh1r)));
            const float zg = 1.f/(1.f + expf(-(xg11 + s1 + bh1z)));
            const float ng = tanhf(xg12 + rg*(s2 + bh1n));
            float hp = 0.f;
            if (t > 0) {
                const int a = ((ug1 >> 3)*16 + r1)*8 + (ug1 & 7);
                hp = bf2f(sAh[a]) + bf2f(sAl[a]);
            }
            const float hn = (1.f - zg)*ng + zg*hp;
            const unsigned short hi = f2bf(hn);
            const unsigned short lo = f2bf(hn - bf2f(hi));
            bstore_u(hout + (size_t)ug1*B_ + b0 + r1,
                     (unsigned)hi | ((unsigned)lo << 16));
        }
        // LDS WAR only (gates' sAh/part2 reads vs next step's writes);
        // h stores intentionally NOT drained — words self-validate.
        barrier_lds();
    }
}

// ---------------------------------------------------------------------------
// K3: heads on temporal2 [t][u][b] packed bf16 hi|lo; h = hi + lo.
// ---------------------------------------------------------------------------
__global__ __launch_bounds__(256) void k_heads2(const unsigned int* __restrict__ temporal2,
                                                const float* __restrict__ Wcat,
                                                const float* __restrict__ bc,
                                                const float* __restrict__ bf,
                                                float* __restrict__ cs,
                                                float* __restrict__ fine_out) {
    const int t = blockIdx.x;       // 0..95
    const int b = threadIdx.x;      // 0..255
    const unsigned int* tb = temporal2 + (size_t)t*HB_ + b;
    float acc[31];
    #pragma unroll
    for (int c = 0; c < 31; ++c) acc[c] = 0.f;
    for (int u = 0; u < H_; ++u) {
        const unsigned int v = tb[(size_t)u*B_];
        const float x = bf2f((unsigned short)(v & 0xffffu)) + bf2f((unsigned short)(v >> 16));
        const float* wrow = Wcat + u*32;
        #pragma unroll
        for (int c = 0; c < 31; ++c) acc[c] = fmaf(x, wrow[c], acc[c]);
    }
    const float l0 = acc[0] + bc[0], l1 = acc[1] + bc[1];
    const float m  = fmaxf(l0, l1);
    const float e0 = expf(l0 - m), e1 = expf(l1 - m);
    const float inv = 1.f/(e0 + e1);
    cs[((size_t)b*T_ + t)*2]     = e0*inv;
    cs[((size_t)b*T_ + t)*2 + 1] = e1*inv;
    #pragma unroll
    for (int c = 2; c < 31; ++c) {
        fine_out[((size_t)b*T_ + t)*NC_ + (c-2)] = 1.f/(1.f + expf(-(acc[c] + bf[c-2])));
    }
}

// ---------------------------------------------------------------------------
// K4: NMS + argmax
// ---------------------------------------------------------------------------
__global__ __launch_bounds__(256) void k_nms(const float* __restrict__ cs,
                                             float* __restrict__ out_dec,
                                             float* __restrict__ out_nms) {
    const int idx = blockIdx.x*256 + threadIdx.x;   // < 24576
    const int t = idx % T_;
    const float bg = cs[idx*2], s1 = cs[idx*2+1];
    float wmin = bg;
    #pragma unroll
    for (int dt = -2; dt <= 2; ++dt) {
        const int tt = t + dt;
        if (dt != 0 && tt >= 0 && tt < T_) wmin = fminf(wmin, cs[(idx + dt)*2]);
    }
    const bool keep = (bg <= wmin);
    out_dec[idx]     = (keep && (s1 > bg)) ? 1.f : 0.f;
    out_nms[idx*2]   = keep ? bg : 0.f;
    out_nms[idx*2+1] = keep ? s1 : 0.f;
}

// ---------------------------------------------------------------------------
extern "C" void kernel_launch(void* const* d_in, const int* in_sizes, int n_in,
                              void* d_out, int out_size, void* d_ws, size_t ws_size,
                              hipStream_t stream) {
    const float* features = (const float*)d_in[0];
    const float* Wi = (const float*)d_in[2];
    const float* Wh = (const float*)d_in[3];
    const float* bi = (const float*)d_in[4];
    const float* bh = (const float*)d_in[5];
    const float* Wc = (const float*)d_in[6];
    const float* bc = (const float*)d_in[7];
    const float* Wf = (const float*)d_in[8];
    const float* bf = (const float*)d_in[9];

    float* out = (float*)d_out;
    float* out_dec  = out;                 // (B,T)     24576
    float* out_nms  = out + BT_;           // (B,T,2)   49152
    float* out_fine = out + BT_ + 2*BT_;   // (B,T,29)  712704

    // workspace: xproj f32 | Wq2 u16 frags | temporal2 u32 | (bar, unused)
    float* xproj = (float*)d_ws;
    unsigned short* Wq2 = (unsigned short*)(xproj + (size_t)BT_*G3_);
    unsigned int* temporal2 = (unsigned int*)((char*)Wq2 + (size_t)WQ2_U16*2);
    float* Wcat = xproj;                   // xproj dead after GRU
    float* cs   = xproj + 12288;

    // phase-1 overlays (dead once consumers below run, stream-ordered):
    //   Bh/Bl (847,872 u16) fits inside Wq2 region (884,736 u16)
    //   Ah/Al (36,175,872 B) == temporal2 region exactly
    unsigned short* Bh16 = (unsigned short*)Wq2;
    unsigned short* Bl16 = Bh16 + (size_t)WQCOLS*F_;
    unsigned short* Ah16 = (unsigned short*)temporal2;
    unsigned short* Al16 = Ah16 + (size_t)BT_*F_;

    k_split_a<<<8832, 256, 0, stream>>>(features, Ah16, Al16);
    k_split_b<<<1656, 256, 0, stream>>>(Wi, Bh16, Bl16);
    k_xproj_mfma<<<dim3(9, 192), 256, 0, stream>>>(Ah16, Al16, Bh16, Bl16, bi, xproj);
    k_prep_wq2<<<432, 256, 0, stream>>>(Wh, Wq2);        // overwrites Bh/Bl (dead)
    k_fill_sent<<<8832, 256, 0, stream>>>(temporal2);    // overwrites Ah/Al (dead); re-poison
    k_gru_all<<<256, 512, 0, stream>>>(xproj, Wq2, bh, temporal2);
    k_prep_wcat<<<46, 256, 0, stream>>>(Wc, Wf, Wcat);
    k_heads2<<<96, 256, 0, stream>>>(temporal2, Wcat, bc, bf, cs, out_fine);
    k_nms<<<96, 256, 0, stream>>>(cs, out_dec, out_nms);
}

// Round 5
// 685.857 us; speedup vs baseline: 1.1666x; 1.1666x over previous
//
#include <hip/hip_runtime.h>
#include <hip/hip_bf16.h>

// Problem constants
#define B_ 256
#define T_ 96
#define F_ 368
#define H_ 368
#define G3_ 1104          // 3*H
#define NC_ 29            // fine classes
#define BT_ (B_*T_)       // 24576
#define HB_ (H_*B_)       // 94208, one time-slice of temporal [u][b]

// GRU geometry
#define NSL 8             // unit slices
#define NU 46             // units per slice (8*46 = 368)
#define NCOL 138          // cols per slice = 3*NU
#define ROWS 8            // batch rows per group
#define WQCOLS 1152       // (legacy name, used for split-B overlay sizing)

// MFMA-GRU geometry: per slice N=138 -> 9 tiles of 16 (cols 138..143 pad),
// K=368 -> 12 k-tiles of 32 (k 368..383 pad). Wq2 frag store:
// [us 8][nt 9][kt 12][plane 2][lane 64][e 8] u16 = 1,769,472 B.
#define WQ2_U16 (8*9*12*2*64*8)

#define F4C(v, i) ((i)==0?(v).x:((i)==1?(v).y:((i)==2?(v).z:(v).w)))

typedef __attribute__((ext_vector_type(8))) short bhalf8;   // 8 bf16 = 4 VGPR
typedef __attribute__((ext_vector_type(4))) float f32x4;

// ---- bf16 split helpers (bit-level RNE, no header dependence) -------------
__device__ __forceinline__ unsigned short f2bf(float x) {
    unsigned u = __float_as_uint(x);
    u += 0x7fffu + ((u >> 16) & 1u);
    return (unsigned short)(u >> 16);
}
__device__ __forceinline__ float bf2f(unsigned short b) {
    return __uint_as_float(((unsigned)b) << 16);
}

// async global->LDS, 16B per lane; lds base must be wave-uniform
__device__ __forceinline__ void gll16(const void* g, void* l) {
    __builtin_amdgcn_global_load_lds(
        (const __attribute__((address_space(1))) void*)g,
        (__attribute__((address_space(3))) void*)l, 16, 0, 0);
}

// ---- fence-free cross-XCD exchange primitives (proven rounds 2-3) ---------
__device__ __forceinline__ int bload_i(const int* p) {
    return __hip_atomic_load(p, __ATOMIC_RELAXED, __HIP_MEMORY_SCOPE_AGENT);
}
__device__ __forceinline__ void bstore_i(int* p, int v) {
    __hip_atomic_store(p, v, __ATOMIC_RELAXED, __HIP_MEMORY_SCOPE_AGENT);
}
__device__ __forceinline__ unsigned int bload_u(const unsigned int* p) {
    return __hip_atomic_load(p, __ATOMIC_RELAXED, __HIP_MEMORY_SCOPE_AGENT);
}
__device__ __forceinline__ void bstore_u(unsigned int* p, unsigned int v) {
    __hip_atomic_store(p, v, __ATOMIC_RELAXED, __HIP_MEMORY_SCOPE_AGENT);
}
__device__ __forceinline__ unsigned long long bload_u2(const unsigned long long* p) {
    return __hip_atomic_load(p, __ATOMIC_RELAXED, __HIP_MEMORY_SCOPE_AGENT);
}

// ---------------------------------------------------------------------------
// K0: pack Wh (1104x368) into bf16 hi/lo B-fragments Wq2.
// ---------------------------------------------------------------------------
__global__ __launch_bounds__(256) void k_prep_wq2(const float* __restrict__ Wh,
                                                  unsigned short* __restrict__ Wq2) {
    const int idx = blockIdx.x*256 + threadIdx.x;   // < 110592 (432 blocks exact)
    const int l = idx & 63;
    const int p = (idx >> 6) & 1;
    int q = idx >> 7;
    const int kt = q % 12; q /= 12;
    const int nt = q % 9;
    const int us = q / 9;
    const int col = nt*16 + (l & 15);
    const int k0 = kt*32 + (l >> 4)*8;              // multiple of 8; 368%8==0
    float v[8];
    #pragma unroll
    for (int e = 0; e < 8; ++e) v[e] = 0.f;
    if (col < NCOL && k0 < H_) {
        const int g = col / NU, uu = col - g*NU;
        const int grow = g*H_ + us*NU + uu;         // < 1104
        const float4 f0 = *reinterpret_cast<const float4*>(Wh + (size_t)grow*H_ + k0);
        const float4 f1 = *reinterpret_cast<const float4*>(Wh + (size_t)grow*H_ + k0 + 4);
        v[0]=f0.x; v[1]=f0.y; v[2]=f0.z; v[3]=f0.w;
        v[4]=f1.x; v[5]=f1.y; v[6]=f1.z; v[7]=f1.w;
    }
    unsigned int o[4];
    #pragma unroll
    for (int e = 0; e < 4; ++e) {
        const unsigned short h0 = f2bf(v[2*e]), h1 = f2bf(v[2*e+1]);
        const unsigned short w0 = p ? f2bf(v[2*e]   - bf2f(h0)) : h0;
        const unsigned short w1 = p ? f2bf(v[2*e+1] - bf2f(h1)) : h1;
        o[e] = (unsigned)w0 | ((unsigned)w1 << 16);
    }
    uint4* dst = reinterpret_cast<uint4*>(Wq2 + (size_t)idx*8);
    *dst = make_uint4(o[0], o[1], o[2], o[3]);
}

// ---------------------------------------------------------------------------
// K0b: pack head weights Wcat[u][32]
// ---------------------------------------------------------------------------
__global__ __launch_bounds__(256) void k_prep_wcat(const float* __restrict__ Wc,
                                                   const float* __restrict__ Wf,
                                                   float* __restrict__ Wcat) {
    const int idx = blockIdx.x*256 + threadIdx.x;   // < 368*32 = 11776
    const int u = idx >> 5, c = idx & 31;
    float v = 0.f;
    if (c < 2) v = Wc[c*H_ + u];
    else if (c < 31) v = Wf[(c-2)*H_ + u];
    Wcat[idx] = v;
}

// ---------------------------------------------------------------------------
// K0c: zero flag words at the coherence point (8192 ints = 32 blocks)
// ---------------------------------------------------------------------------
__global__ __launch_bounds__(256) void k_zero_bar(int* __restrict__ bar) {
    __hip_atomic_store(bar + blockIdx.x*256 + threadIdx.x, 0,
                       __ATOMIC_RELAXED, __HIP_MEMORY_SCOPE_AGENT);
}

// ---------------------------------------------------------------------------
// K0d: split features into hi/lo bf16 planes (Markidis split).
// ---------------------------------------------------------------------------
__global__ __launch_bounds__(256) void k_split_a(const float* __restrict__ src,
                                                 unsigned short* __restrict__ Ah,
                                                 unsigned short* __restrict__ Al) {
    const int idx = blockIdx.x*256 + threadIdx.x;
    const float4 v = reinterpret_cast<const float4*>(src)[idx];
    ushort4 h, lo;
    h.x = f2bf(v.x); lo.x = f2bf(v.x - bf2f(h.x));
    h.y = f2bf(v.y); lo.y = f2bf(v.y - bf2f(h.y));
    h.z = f2bf(v.z); lo.z = f2bf(v.z - bf2f(h.z));
    h.w = f2bf(v.w); lo.w = f2bf(v.w - bf2f(h.w));
    reinterpret_cast<ushort4*>(Ah)[idx] = h;
    reinterpret_cast<ushort4*>(Al)[idx] = lo;
}

// K0e: split Wi (1104x368) into hi/lo bf16, zero-padded to 1152 N-rows.
__global__ __launch_bounds__(256) void k_split_b(const float* __restrict__ Wi,
                                                 unsigned short* __restrict__ Bh,
                                                 unsigned short* __restrict__ Bl) {
    const int idx = blockIdx.x*256 + threadIdx.x;
    const float x = (idx < G3_*F_) ? Wi[idx] : 0.f;
    const unsigned short h = f2bf(x);
    Bh[idx] = h;
    Bl[idx] = f2bf(x - bf2f(h));
}

// ---------------------------------------------------------------------------
// K1: xproj GEMM via split-bf16 MFMA (proven round-1 kernel, unchanged).
// ---------------------------------------------------------------------------
__global__ __launch_bounds__(256) void k_xproj_mfma(
        const unsigned short* __restrict__ Ah, const unsigned short* __restrict__ Al,
        const unsigned short* __restrict__ Bh, const unsigned short* __restrict__ Bl,
        const float* __restrict__ bias, float* __restrict__ C)
{
    __shared__ unsigned short sAh[128*32], sAl[128*32], sBh[128*32], sBl[128*32];
    const int tid = threadIdx.x;
    const int w   = tid >> 6, l = tid & 63;
    const int gm0 = blockIdx.y * 128, gn0 = blockIdx.x * 128;

    const int srow = tid >> 2;                       // 0..63
    const int cg   = (tid & 3) ^ ((tid >> 3) & 3);   // source k-chunk (0..3)
    const size_t aoff0 = (size_t)(gm0 + srow)      * F_ + cg * 8;
    const size_t aoff1 = (size_t)(gm0 + srow + 64) * F_ + cg * 8;
    const size_t boff0 = (size_t)(gn0 + srow)      * F_ + cg * 8;
    const size_t boff1 = (size_t)(gn0 + srow + 64) * F_ + cg * 8;
    const int lb0 = w * 1024, lb1 = 4096 + w * 1024; // wave-uniform LDS bases

    const int lr = l & 15, lk = l >> 4;
    const int cswz = (lk ^ ((lr >> 1) & 3)) * 16;
    const int wr = w >> 1, wc = w & 1;
    int offA[4], offB[4];
    #pragma unroll
    for (int f = 0; f < 4; ++f) {
        offA[f] = (wr*64 + f*16 + lr) * 64 + cswz;
        offB[f] = (wc*64 + f*16 + lr) * 64 + cswz;
    }

    f32x4 acc[4][4];
    #pragma unroll
    for (int i = 0; i < 4; ++i)
        #pragma unroll
        for (int j = 0; j < 4; ++j) acc[i][j] = f32x4{0.f,0.f,0.f,0.f};

    auto stage = [&](int kt) {
        const size_t ko = (size_t)kt * 32;
        gll16(Ah + aoff0 + ko, (char*)sAh + lb0);
        gll16(Ah + aoff1 + ko, (char*)sAh + lb1);
        gll16(Al + aoff0 + ko, (char*)sAl + lb0);
        gll16(Al + aoff1 + ko, (char*)sAl + lb1);
        gll16(Bh + boff0 + ko, (char*)sBh + lb0);
        gll16(Bh + boff1 + ko, (char*)sBh + lb1);
        gll16(Bl + boff0 + ko, (char*)sBl + lb0);
        gll16(Bl + boff1 + ko, (char*)sBl + lb1);
    };

    stage(0);
    for (int kt = 0; kt < 12; ++kt) {
        __syncthreads();
        if (kt == 11) {
            if (cg >= 2) {
                const f32x4 z = f32x4{0.f,0.f,0.f,0.f};
                *reinterpret_cast<f32x4*>((char*)sAh + tid*16)        = z;
                *reinterpret_cast<f32x4*>((char*)sAh + tid*16 + 4096) = z;
                *reinterpret_cast<f32x4*>((char*)sAl + tid*16)        = z;
                *reinterpret_cast<f32x4*>((char*)sAl + tid*16 + 4096) = z;
                *reinterpret_cast<f32x4*>((char*)sBh + tid*16)        = z;
                *reinterpret_cast<f32x4*>((char*)sBh + tid*16 + 4096) = z;
                *reinterpret_cast<f32x4*>((char*)sBl + tid*16)        = z;
                *reinterpret_cast<f32x4*>((char*)sBl + tid*16 + 4096) = z;
            }
            __syncthreads();
        }
        bhalf8 fAh[4], fAl[4], fBh[4], fBl[4];
        #pragma unroll
        for (int f = 0; f < 4; ++f) {
            fAh[f] = *reinterpret_cast<const bhalf8*>((const char*)sAh + offA[f]);
            fAl[f] = *reinterpret_cast<const bhalf8*>((const char*)sAl + offA[f]);
            fBh[f] = *reinterpret_cast<const bhalf8*>((const char*)sBh + offB[f]);
            fBl[f] = *reinterpret_cast<const bhalf8*>((const char*)sBl + offB[f]);
        }
        __syncthreads();
        if (kt < 11) stage(kt + 1);
        #pragma unroll
        for (int i = 0; i < 4; ++i)
            #pragma unroll
            for (int j = 0; j < 4; ++j) {
                acc[i][j] = __builtin_amdgcn_mfma_f32_16x16x32_bf16(fAh[i], fBh[j], acc[i][j], 0, 0, 0);
                acc[i][j] = __builtin_amdgcn_mfma_f32_16x16x32_bf16(fAh[i], fBl[j], acc[i][j], 0, 0, 0);
                acc[i][j] = __builtin_amdgcn_mfma_f32_16x16x32_bf16(fAl[i], fBh[j], acc[i][j], 0, 0, 0);
            }
    }

    #pragma unroll
    for (int j = 0; j < 4; ++j) {
        const int gcol = gn0 + wc*64 + j*16 + lr;
        if (gcol < G3_) {
            const float bv = bias[gcol];
            #pragma unroll
            for (int i = 0; i < 4; ++i) {
                const int grow = gm0 + wr*64 + i*16 + lk*4;
                float* cp = C + (size_t)grow * G3_ + gcol;
                #pragma unroll
                for (int q = 0; q < 4; ++q)
                    cp[(size_t)q * G3_] = acc[i][j][q] + bv;
            }
        }
    }
}

// ---------------------------------------------------------------------------
// K2 v12: PERSISTENT MFMA GRU = round-3 (v10) protocol + exchange-path cuts.
// Changes vs v10 (arithmetic bit-identical):
//  - flag lines PADDED: one 128B line per (bg,slice) producer. v10 packed
//    all 8 slice flags of a bg into one line -> 8 writers + 512 pollers
//    ping-ponged a single L3 line every step.
//  - per-wave EARLY flag publish: each gate wave drains its OWN vmcnt and
//    lane0 publishes flag word w right away; the consumer-visible publish
//    no longer waits for the terminal whole-WG barrier (removes barrier +
//    inter-wave skew from the serial chain). Same release argument: the
//    wave-level vmcnt(0) proves that wave's h bypass stores are at the
//    coherence point; consumer needs flags of all 6 gate waves.
//  - stage via 8B loads: 184 uint2 per slice instead of 368 u32.
// ---------------------------------------------------------------------------
__global__ __launch_bounds__(512, 2) void k_gru_all(const float* __restrict__ xproj,
                                                    const unsigned short* __restrict__ Wq2,
                                                    const float* __restrict__ bh,
                                                    unsigned int* __restrict__ h2,
                                                    int* __restrict__ bar) {
    __shared__ unsigned short sAh[48*16*8];     // [k-chunk][row16][e8], 12288 B
    __shared__ unsigned short sAl[48*16*8];     // 12288 B
    __shared__ float part2[4][144][9];          // [wk][col][row+pad], 20736 B
    const int tid = threadIdx.x;
    const int us  = blockIdx.x & 7;             // this WG's slice
    const int bg  = blockIdx.x >> 3;            // 0..31
    const int b0  = bg * ROWS;
    const int w   = tid >> 6;                   // wave 0..7
    const int l   = tid & 63;
    const int wk  = w >> 1;                     // K quarter (3 k-tiles)
    const int wn  = w & 1;                      // N half: tiles wn*4..wn*4+4
    const int nt0 = wn * 4;
    // flag lines: 32 ints (128 B) per (bg,slice); single writer-WG per line
    int* myline = bar + (bg*8 + us)*32;         // this WG publishes words 0..5
    int* pline  = bar + (bg*8 + w)*32;          // wave w polls producer slice w

    // zero-init LDS: A pad rows/chunks stay 0 forever; part2 zero for t=0
    for (int s = tid; s < 48*16*8; s += 512) { sAh[s] = 0; sAl[s] = 0; }
    for (int s = tid; s < 4*144*9; s += 512) (&part2[0][0][0])[s] = 0.f;

    // preload static B fragments: 5 tiles x 3 k-tiles x 2 planes = 120 VGPR
    bhalf8 bB[5][3][2];
    #pragma unroll
    for (int ti = 0; ti < 5; ++ti)
        #pragma unroll
        for (int kti = 0; kti < 3; ++kti)
            #pragma unroll
            for (int p = 0; p < 2; ++p)
                bB[ti][kti][p] = *reinterpret_cast<const bhalf8*>(
                    Wq2 + ((((size_t)(us*9 + nt0 + ti)*12 + (wk*3 + kti))*2 + p)*64 + l)*8);

    // gate-phase constants (one item per thread, tid < 368)
    const bool gact = tid < ROWS*NU;
    const int u1 = tid % NU, r1 = tid / NU;
    const int ug1 = us*NU + u1;
    float bh1r = 0.f, bh1z = 0.f, bh1n = 0.f;
    if (gact) { bh1r = bh[ug1]; bh1z = bh[H_+ug1]; bh1n = bh[2*H_+ug1]; }

    // staging geometry: wave w stages slice w as 184 uint2 (rows paired)
    int goff[3], aoff2[3]; bool sact[3];
    #pragma unroll
    for (int ii = 0; ii < 3; ++ii) {
        const int pi = l + ii*64;
        sact[ii] = pi < 184;
        const int pc = sact[ii] ? pi : 0;
        const int u = NU*w + (pc >> 2), r2 = pc & 3;
        goff[ii]  = u*B_ + b0 + 2*r2;
        aoff2[ii] = ((u >> 3)*16 + 2*r2)*8 + (u & 7);
    }

    // per-lane A-frag LDS byte offset within a k-tile block (1024 B / k-tile)
    const int aoffb = (l >> 4)*256 + (l & 15)*16;

    __syncthreads();

    for (int t = 0; t < T_; ++t) {
        unsigned int* hout = h2 + (size_t)t*HB_;

        // prefetch gate operands (independent of h; hides under poll)
        float xg10 = 0.f, xg11 = 0.f, xg12 = 0.f;
        if (gact) {
            const float* xr1 = xproj + ((size_t)(b0 + r1)*T_ + t)*G3_;
            xg10 = xr1[ug1]; xg11 = xr1[H_+ug1]; xg12 = xr1[2*H_+ug1];
        }

        if (t > 0) {
            // wait for all 6 gate-wave flags of producer slice w (lanes 0..5
            // each own one flag word; padded line, single writer WG)
            {
                int f;
                do { f = (l < 6) ? bload_i(pline + l) : t; } while (__any(f < t));
            }
            const unsigned int* hin = h2 + (size_t)(t - 1)*HB_;
            #pragma unroll
            for (int ii = 0; ii < 3; ++ii) {
                if (sact[ii]) {
                    const unsigned long long v = bload_u2(
                        reinterpret_cast<const unsigned long long*>(hin + goff[ii]));
                    const unsigned int v0 = (unsigned int)v;
                    const unsigned int v1 = (unsigned int)(v >> 32);
                    const int a = aoff2[ii];
                    sAh[a]     = (unsigned short)(v0 & 0xffffu);
                    sAl[a]     = (unsigned short)(v0 >> 16);
                    sAh[a + 8] = (unsigned short)(v1 & 0xffffu);
                    sAl[a + 8] = (unsigned short)(v1 >> 16);
                }
            }
            __syncthreads();
            // MFMA: 3 k-tiles x 5 n-tiles x 3 split terms = 45 MFMAs/wave
            f32x4 acc[5];
            #pragma unroll
            for (int ti = 0; ti < 5; ++ti) acc[ti] = f32x4{0.f,0.f,0.f,0.f};
            #pragma unroll
            for (int kti = 0; kti < 3; ++kti) {
                const int kt = wk*3 + kti;
                const bhalf8 fh = *reinterpret_cast<const bhalf8*>((const char*)sAh + kt*1024 + aoffb);
                const bhalf8 fl = *reinterpret_cast<const bhalf8*>((const char*)sAl + kt*1024 + aoffb);
                #pragma unroll
                for (int ti = 0; ti < 5; ++ti) {
                    acc[ti] = __builtin_amdgcn_mfma_f32_16x16x32_bf16(fh, bB[ti][kti][0], acc[ti], 0, 0, 0);
                    acc[ti] = __builtin_amdgcn_mfma_f32_16x16x32_bf16(fh, bB[ti][kti][1], acc[ti], 0, 0, 0);
                    acc[ti] = __builtin_amdgcn_mfma_f32_16x16x32_bf16(fl, bB[ti][kti][0], acc[ti], 0, 0, 0);
                }
            }
            // C frags -> per-wk partials (padded, conflict-free).
            // C layout: col=lane&15, row=(lane>>4)*4+reg; rows 0..7 in lanes 0..31.
            if (l < 32) {
                #pragma unroll
                for (int ti = 0; ti < 5; ++ti) {
                    const int col = (nt0 + ti)*16 + (l & 15);
                    float* pp = &part2[wk][col][(l >> 4)*4];
                    pp[0] = acc[ti][0]; pp[1] = acc[ti][1];
                    pp[2] = acc[ti][2]; pp[3] = acc[ti][3];
                }
            }
        }
        __syncthreads();

        // fused gates: one (unit,row) per thread
        if (gact) {
            float s0 = 0.f, s1 = 0.f, s2 = 0.f;
            #pragma unroll
            for (int q2 = 0; q2 < 4; ++q2) {
                s0 += part2[q2][u1][r1];
                s1 += part2[q2][NU + u1][r1];
                s2 += part2[q2][2*NU + u1][r1];
            }
            const float rg = 1.f/(1.f + expf(-(xg10 + s0 + bh1r)));
            const float zg = 1.f/(1.f + expf(-(xg11 + s1 + bh1z)));
            const float ng = tanhf(xg12 + rg*(s2 + bh1n));
            float hp = 0.f;
            if (t > 0) {
                const int a = ((ug1 >> 3)*16 + r1)*8 + (ug1 & 7);
                hp = bf2f(sAh[a]) + bf2f(sAl[a]);
            }
            const float hn = (1.f - zg)*ng + zg*hp;
            const unsigned short hi = f2bf(hn);
            const unsigned short lo = f2bf(hn - bf2f(hi));
            bstore_u(hout + (size_t)ug1*B_ + b0 + r1,
                     (unsigned)hi | ((unsigned)lo << 16));
        }
        // per-wave early publish: wave-level vmcnt(0) proves this wave's h
        // bypass stores reached the coherence point; then lane0 fires flag.
        if (w < 6) {
            asm volatile("s_waitcnt vmcnt(0)" ::: "memory");
            if (l == 0) bstore_i(myline + w, t + 1);
        }
        // terminal barrier: LDS WAR only (off the consumer-visible path)
        __syncthreads();
    }
}

// ---------------------------------------------------------------------------
// K3: heads on temporal2 [t][u][b] packed bf16 hi|lo; h = hi + lo.
// ---------------------------------------------------------------------------
__global__ __launch_bounds__(256) void k_heads2(const unsigned int* __restrict__ temporal2,
                                                const float* __restrict__ Wcat,
                                                const float* __restrict__ bc,
                                                const float* __restrict__ bf,
                                                float* __restrict__ cs,
                                                float* __restrict__ fine_out) {
    const int t = blockIdx.x;       // 0..95
    const int b = threadIdx.x;      // 0..255
    const unsigned int* tb = temporal2 + (size_t)t*HB_ + b;
    float acc[31];
    #pragma unroll
    for (int c = 0; c < 31; ++c) acc[c] = 0.f;
    for (int u = 0; u < H_; ++u) {
        const unsigned int v = tb[(size_t)u*B_];
        const float x = bf2f((unsigned short)(v & 0xffffu)) + bf2f((unsigned short)(v >> 16));
        const float* wrow = Wcat + u*32;
        #pragma unroll
        for (int c = 0; c < 31; ++c) acc[c] = fmaf(x, wrow[c], acc[c]);
    }
    const float l0 = acc[0] + bc[0], l1 = acc[1] + bc[1];
    const float m  = fmaxf(l0, l1);
    const float e0 = expf(l0 - m), e1 = expf(l1 - m);
    const float inv = 1.f/(e0 + e1);
    cs[((size_t)b*T_ + t)*2]     = e0*inv;
    cs[((size_t)b*T_ + t)*2 + 1] = e1*inv;
    #pragma unroll
    for (int c = 2; c < 31; ++c) {
        fine_out[((size_t)b*T_ + t)*NC_ + (c-2)] = 1.f/(1.f + expf(-(acc[c] + bf[c-2])));
    }
}

// ---------------------------------------------------------------------------
// K4: NMS + argmax
// ---------------------------------------------------------------------------
__global__ __launch_bounds__(256) void k_nms(const float* __restrict__ cs,
                                             float* __restrict__ out_dec,
                                             float* __restrict__ out_nms) {
    const int idx = blockIdx.x*256 + threadIdx.x;   // < 24576
    const int t = idx % T_;
    const float bg = cs[idx*2], s1 = cs[idx*2+1];
    float wmin = bg;
    #pragma unroll
    for (int dt = -2; dt <= 2; ++dt) {
        const int tt = t + dt;
        if (dt != 0 && tt >= 0 && tt < T_) wmin = fminf(wmin, cs[(idx + dt)*2]);
    }
    const bool keep = (bg <= wmin);
    out_dec[idx]     = (keep && (s1 > bg)) ? 1.f : 0.f;
    out_nms[idx*2]   = keep ? bg : 0.f;
    out_nms[idx*2+1] = keep ? s1 : 0.f;
}

// ---------------------------------------------------------------------------
extern "C" void kernel_launch(void* const* d_in, const int* in_sizes, int n_in,
                              void* d_out, int out_size, void* d_ws, size_t ws_size,
                              hipStream_t stream) {
    const float* features = (const float*)d_in[0];
    const float* Wi = (const float*)d_in[2];
    const float* Wh = (const float*)d_in[3];
    const float* bi = (const float*)d_in[4];
    const float* bh = (const float*)d_in[5];
    const float* Wc = (const float*)d_in[6];
    const float* bc = (const float*)d_in[7];
    const float* Wf = (const float*)d_in[8];
    const float* bf = (const float*)d_in[9];

    float* out = (float*)d_out;
    float* out_dec  = out;                 // (B,T)     24576
    float* out_nms  = out + BT_;           // (B,T,2)   49152
    float* out_fine = out + BT_ + 2*BT_;   // (B,T,29)  712704

    // workspace: xproj f32 | Wq2 u16 frags | temporal2 u32 | bar (8192 ints)
    float* xproj = (float*)d_ws;
    unsigned short* Wq2 = (unsigned short*)(xproj + (size_t)BT_*G3_);
    unsigned int* temporal2 = (unsigned int*)((char*)Wq2 + (size_t)WQ2_U16*2);
    int* bar = (int*)(temporal2 + (size_t)T_*HB_);
    float* Wcat = xproj;                   // xproj dead after GRU
    float* cs   = xproj + 12288;

    // phase-1 overlays (dead once consumers below run, stream-ordered):
    //   Bh/Bl (847,872 u16) fits inside Wq2 region (884,736 u16)
    //   Ah/Al (36,175,872 B) == temporal2 region exactly
    unsigned short* Bh16 = (unsigned short*)Wq2;
    unsigned short* Bl16 = Bh16 + (size_t)WQCOLS*F_;
    unsigned short* Ah16 = (unsigned short*)temporal2;
    unsigned short* Al16 = Ah16 + (size_t)BT_*F_;

    k_zero_bar<<<32, 256, 0, stream>>>(bar);
    k_split_a<<<8832, 256, 0, stream>>>(features, Ah16, Al16);
    k_split_b<<<1656, 256, 0, stream>>>(Wi, Bh16, Bl16);
    k_xproj_mfma<<<dim3(9, 192), 256, 0, stream>>>(Ah16, Al16, Bh16, Bl16, bi, xproj);
    k_prep_wq2<<<432, 256, 0, stream>>>(Wh, Wq2);        // overwrites Bh/Bl (dead)
    k_gru_all<<<256, 512, 0, stream>>>(xproj, Wq2, bh, temporal2, bar); // overwrites Ah/Al (dead)
    k_prep_wcat<<<46, 256, 0, stream>>>(Wc, Wf, Wcat);
    k_heads2<<<96, 256, 0, stream>>>(temporal2, Wcat, bc, bf, cs, out_fine);
    k_nms<<<96, 256, 0, stream>>>(cs, out_dec, out_nms);
}

// Round 7
// 597.668 us; speedup vs baseline: 1.3388x; 1.1476x over previous
//
#include <hip/hip_runtime.h>
#include <hip/hip_bf16.h>

// Problem constants
#define B_ 256
#define T_ 96
#define F_ 368
#define H_ 368
#define G3_ 1104          // 3*H
#define NC_ 29            // fine classes
#define BT_ (B_*T_)       // 24576
#define HB_ (H_*B_)       // 94208, one time-slice of h2 [bg][u][r]

// GRU geometry
#define NSL 8             // unit slices
#define NU 46             // units per slice (8*46 = 368)
#define NCOL 138          // cols per slice = 3*NU
#define ROWS 8            // batch rows per group
#define WQCOLS 1152       // (legacy name, used for split-B overlay sizing)

// MFMA-GRU geometry: per slice N=138 -> 9 tiles of 16 (cols 138..143 pad),
// K=368 -> 12 k-tiles of 32 (k 368..383 pad). Wq2 frag store:
// [us 8][nt 9][kt 12][plane 2][lane 64][e 8] u16 = 1,769,472 B.
#define WQ2_U16 (8*9*12*2*64*8)

// h-word sentinel: hi half 0x7FC0 = bf16 NaN; finite h can never produce it,
// so a non-sentinel full-word read proves the producer's store landed.
#define SENT 0x7FC07FC0u

#define F4C(v, i) ((i)==0?(v).x:((i)==1?(v).y:((i)==2?(v).z:(v).w)))

typedef __attribute__((ext_vector_type(8))) short bhalf8;   // 8 bf16 = 4 VGPR
typedef __attribute__((ext_vector_type(4))) float f32x4;

// ---- bf16 split helpers (bit-level RNE, no header dependence) -------------
__device__ __forceinline__ unsigned short f2bf(float x) {
    unsigned u = __float_as_uint(x);
    u += 0x7fffu + ((u >> 16) & 1u);
    return (unsigned short)(u >> 16);
}
__device__ __forceinline__ float bf2f(unsigned short b) {
    return __uint_as_float(((unsigned)b) << 16);
}

// async global->LDS, 16B per lane; lds base must be wave-uniform
__device__ __forceinline__ void gll16(const void* g, void* l) {
    __builtin_amdgcn_global_load_lds(
        (const __attribute__((address_space(1))) void*)g,
        (__attribute__((address_space(3))) void*)l, 16, 0, 0);
}

// ---- fence-free cross-XCD exchange primitives ----------------------------
__device__ __forceinline__ unsigned int bload_u(const unsigned int* p) {
    return __hip_atomic_load(p, __ATOMIC_RELAXED, __HIP_MEMORY_SCOPE_AGENT);
}
__device__ __forceinline__ void bstore_u(unsigned int* p, unsigned int v) {
    __hip_atomic_store(p, v, __ATOMIC_RELAXED, __HIP_MEMORY_SCOPE_AGENT);
}
__device__ __forceinline__ unsigned long long bload_u2(const unsigned long long* p) {
    return __hip_atomic_load(p, __ATOMIC_RELAXED, __HIP_MEMORY_SCOPE_AGENT);
}

// LDS-only barrier: orders ds ops across the WG WITHOUT draining vmcnt, so
// in-flight agent-scope h stores keep flying across step boundaries.
__device__ __forceinline__ void barrier_lds() {
    asm volatile("s_waitcnt lgkmcnt(0)\ns_barrier" ::: "memory");
}

// ---------------------------------------------------------------------------
// K0: pack Wh (1104x368) into bf16 hi/lo B-fragments Wq2.
// ---------------------------------------------------------------------------
__global__ __launch_bounds__(256) void k_prep_wq2(const float* __restrict__ Wh,
                                                  unsigned short* __restrict__ Wq2) {
    const int idx = blockIdx.x*256 + threadIdx.x;   // < 110592 (432 blocks exact)
    const int l = idx & 63;
    const int p = (idx >> 6) & 1;
    int q = idx >> 7;
    const int kt = q % 12; q /= 12;
    const int nt = q % 9;
    const int us = q / 9;
    const int col = nt*16 + (l & 15);
    const int k0 = kt*32 + (l >> 4)*8;              // multiple of 8; 368%8==0
    float v[8];
    #pragma unroll
    for (int e = 0; e < 8; ++e) v[e] = 0.f;
    if (col < NCOL && k0 < H_) {
        const int g = col / NU, uu = col - g*NU;
        const int grow = g*H_ + us*NU + uu;         // < 1104
        const float4 f0 = *reinterpret_cast<const float4*>(Wh + (size_t)grow*H_ + k0);
        const float4 f1 = *reinterpret_cast<const float4*>(Wh + (size_t)grow*H_ + k0 + 4);
        v[0]=f0.x; v[1]=f0.y; v[2]=f0.z; v[3]=f0.w;
        v[4]=f1.x; v[5]=f1.y; v[6]=f1.z; v[7]=f1.w;
    }
    unsigned int o[4];
    #pragma unroll
    for (int e = 0; e < 4; ++e) {
        const unsigned short h0 = f2bf(v[2*e]), h1 = f2bf(v[2*e+1]);
        const unsigned short w0 = p ? f2bf(v[2*e]   - bf2f(h0)) : h0;
        const unsigned short w1 = p ? f2bf(v[2*e+1] - bf2f(h1)) : h1;
        o[e] = (unsigned)w0 | ((unsigned)w1 << 16);
    }
    uint4* dst = reinterpret_cast<uint4*>(Wq2 + (size_t)idx*8);
    *dst = make_uint4(o[0], o[1], o[2], o[3]);
}

// ---------------------------------------------------------------------------
// K0b: pack head weights Wcat[u][32]
// ---------------------------------------------------------------------------
__global__ __launch_bounds__(256) void k_prep_wcat(const float* __restrict__ Wc,
                                                   const float* __restrict__ Wf,
                                                   float* __restrict__ Wcat) {
    const int idx = blockIdx.x*256 + threadIdx.x;   // < 368*32 = 11776
    const int u = idx >> 5, c = idx & 31;
    float v = 0.f;
    if (c < 2) v = Wc[c*H_ + u];
    else if (c < 31) v = Wf[(c-2)*H_ + u];
    Wcat[idx] = v;
}

// ---------------------------------------------------------------------------
// K0f: fill the h-exchange buffer with the sentinel (re-poison each launch).
// 8832*256*4 u32 == 96*32*368*8 exactly.
// ---------------------------------------------------------------------------
__global__ __launch_bounds__(256) void k_fill_sent(unsigned int* __restrict__ p) {
    const int idx = blockIdx.x*256 + threadIdx.x;
    reinterpret_cast<uint4*>(p)[idx] = make_uint4(SENT, SENT, SENT, SENT);
}

// ---------------------------------------------------------------------------
// K0d: split features into hi/lo bf16 planes (Markidis split).
// ---------------------------------------------------------------------------
__global__ __launch_bounds__(256) void k_split_a(const float* __restrict__ src,
                                                 unsigned short* __restrict__ Ah,
                                                 unsigned short* __restrict__ Al) {
    const int idx = blockIdx.x*256 + threadIdx.x;
    const float4 v = reinterpret_cast<const float4*>(src)[idx];
    ushort4 h, lo;
    h.x = f2bf(v.x); lo.x = f2bf(v.x - bf2f(h.x));
    h.y = f2bf(v.y); lo.y = f2bf(v.y - bf2f(h.y));
    h.z = f2bf(v.z); lo.z = f2bf(v.z - bf2f(h.z));
    h.w = f2bf(v.w); lo.w = f2bf(v.w - bf2f(h.w));
    reinterpret_cast<ushort4*>(Ah)[idx] = h;
    reinterpret_cast<ushort4*>(Al)[idx] = lo;
}

// K0e: split Wi (1104x368) into hi/lo bf16, zero-padded to 1152 N-rows.
__global__ __launch_bounds__(256) void k_split_b(const float* __restrict__ Wi,
                                                 unsigned short* __restrict__ Bh,
                                                 unsigned short* __restrict__ Bl) {
    const int idx = blockIdx.x*256 + threadIdx.x;
    const float x = (idx < G3_*F_) ? Wi[idx] : 0.f;
    const unsigned short h = f2bf(x);
    Bh[idx] = h;
    Bl[idx] = f2bf(x - bf2f(h));
}

// ---------------------------------------------------------------------------
// K1: xproj GEMM via split-bf16 MFMA (proven round-1 kernel, unchanged).
// ---------------------------------------------------------------------------
__global__ __launch_bounds__(256) void k_xproj_mfma(
        const unsigned short* __restrict__ Ah, const unsigned short* __restrict__ Al,
        const unsigned short* __restrict__ Bh, const unsigned short* __restrict__ Bl,
        const float* __restrict__ bias, float* __restrict__ C)
{
    __shared__ unsigned short sAh[128*32], sAl[128*32], sBh[128*32], sBl[128*32];
    const int tid = threadIdx.x;
    const int w   = tid >> 6, l = tid & 63;
    const int gm0 = blockIdx.y * 128, gn0 = blockIdx.x * 128;

    const int srow = tid >> 2;                       // 0..63
    const int cg   = (tid & 3) ^ ((tid >> 3) & 3);   // source k-chunk (0..3)
    const size_t aoff0 = (size_t)(gm0 + srow)      * F_ + cg * 8;
    const size_t aoff1 = (size_t)(gm0 + srow + 64) * F_ + cg * 8;
    const size_t boff0 = (size_t)(gn0 + srow)      * F_ + cg * 8;
    const size_t boff1 = (size_t)(gn0 + srow + 64) * F_ + cg * 8;
    const int lb0 = w * 1024, lb1 = 4096 + w * 1024; // wave-uniform LDS bases

    const int lr = l & 15, lk = l >> 4;
    const int cswz = (lk ^ ((lr >> 1) & 3)) * 16;
    const int wr = w >> 1, wc = w & 1;
    int offA[4], offB[4];
    #pragma unroll
    for (int f = 0; f < 4; ++f) {
        offA[f] = (wr*64 + f*16 + lr) * 64 + cswz;
        offB[f] = (wc*64 + f*16 + lr) * 64 + cswz;
    }

    f32x4 acc[4][4];
    #pragma unroll
    for (int i = 0; i < 4; ++i)
        #pragma unroll
        for (int j = 0; j < 4; ++j) acc[i][j] = f32x4{0.f,0.f,0.f,0.f};

    auto stage = [&](int kt) {
        const size_t ko = (size_t)kt * 32;
        gll16(Ah + aoff0 + ko, (char*)sAh + lb0);
        gll16(Ah + aoff1 + ko, (char*)sAh + lb1);
        gll16(Al + aoff0 + ko, (char*)sAl + lb0);
        gll16(Al + aoff1 + ko, (char*)sAl + lb1);
        gll16(Bh + boff0 + ko, (char*)sBh + lb0);
        gll16(Bh + boff1 + ko, (char*)sBh + lb1);
        gll16(Bl + boff0 + ko, (char*)sBl + lb0);
        gll16(Bl + boff1 + ko, (char*)sBl + lb1);
    };

    stage(0);
    for (int kt = 0; kt < 12; ++kt) {
        __syncthreads();
        if (kt == 11) {
            if (cg >= 2) {
                const f32x4 z = f32x4{0.f,0.f,0.f,0.f};
                *reinterpret_cast<f32x4*>((char*)sAh + tid*16)        = z;
                *reinterpret_cast<f32x4*>((char*)sAh + tid*16 + 4096) = z;
                *reinterpret_cast<f32x4*>((char*)sAl + tid*16)        = z;
                *reinterpret_cast<f32x4*>((char*)sAl + tid*16 + 4096) = z;
                *reinterpret_cast<f32x4*>((char*)sBh + tid*16)        = z;
                *reinterpret_cast<f32x4*>((char*)sBh + tid*16 + 4096) = z;
                *reinterpret_cast<f32x4*>((char*)sBl + tid*16)        = z;
                *reinterpret_cast<f32x4*>((char*)sBl + tid*16 + 4096) = z;
            }
            __syncthreads();
        }
        bhalf8 fAh[4], fAl[4], fBh[4], fBl[4];
        #pragma unroll
        for (int f = 0; f < 4; ++f) {
            fAh[f] = *reinterpret_cast<const bhalf8*>((const char*)sAh + offA[f]);
            fAl[f] = *reinterpret_cast<const bhalf8*>((const char*)sAl + offA[f]);
            fBh[f] = *reinterpret_cast<const bhalf8*>((const char*)sBh + offB[f]);
            fBl[f] = *reinterpret_cast<const bhalf8*>((const char*)sBl + offB[f]);
        }
        __syncthreads();
        if (kt < 11) stage(kt + 1);
        #pragma unroll
        for (int i = 0; i < 4; ++i)
            #pragma unroll
            for (int j = 0; j < 4; ++j) {
                acc[i][j] = __builtin_amdgcn_mfma_f32_16x16x32_bf16(fAh[i], fBh[j], acc[i][j], 0, 0, 0);
                acc[i][j] = __builtin_amdgcn_mfma_f32_16x16x32_bf16(fAh[i], fBl[j], acc[i][j], 0, 0, 0);
                acc[i][j] = __builtin_amdgcn_mfma_f32_16x16x32_bf16(fAl[i], fBh[j], acc[i][j], 0, 0, 0);
            }
    }

    #pragma unroll
    for (int j = 0; j < 4; ++j) {
        const int gcol = gn0 + wc*64 + j*16 + lr;
        if (gcol < G3_) {
            const float bv = bias[gcol];
            #pragma unroll
            for (int i = 0; i < 4; ++i) {
                const int grow = gm0 + wr*64 + i*16 + lk*4;
                float* cp = C + (size_t)grow * G3_ + gcol;
                #pragma unroll
                for (int q = 0; q < 4; ++q)
                    cp[(size_t)q * G3_] = acc[i][j][q] + bv;
            }
        }
    }
}

// ---------------------------------------------------------------------------
// K2 v13: PERSISTENT MFMA GRU, per-word sentinel polling + dense exchange.
// Changes vs v12 (arithmetic bit-identical):
//  - h2 layout [t][bg][u 368][r 8]: producer WG block dense (11.8 KB),
//    consumer slice contiguous (1.47 KB) -> coalesced u64 reads, no
//    read/write sector amplification.
//  - consumer polls DATA words (sentinel-tagged), re-issuing ONLY straggler
//    words (round-4's storm fixed by exec-masked per-word retry). Deletes
//    flags, flag RT, poll RT, and the producer vmcnt-drain entirely.
//  - all per-step barriers are {s_waitcnt lgkmcnt(0); s_barrier}: h stores
//    are fire-and-forget; eventual visibility + per-word validation.
// ---------------------------------------------------------------------------
__global__ __launch_bounds__(512, 2) void k_gru_all(const float* __restrict__ xproj,
                                                    const unsigned short* __restrict__ Wq2,
                                                    const float* __restrict__ bh,
                                                    unsigned int* __restrict__ h2) {
    __shared__ unsigned short sAh[48*16*8];     // [k-chunk][row16][e8], 12288 B
    __shared__ unsigned short sAl[48*16*8];     // 12288 B
    __shared__ float part2[4][144][9];          // [wk][col][row+pad], 20736 B
    const int tid = threadIdx.x;
    const int us  = blockIdx.x & 7;             // this WG's slice
    const int bg  = blockIdx.x >> 3;            // 0..31
    const int b0  = bg * ROWS;
    const int w   = tid >> 6;                   // wave 0..7
    const int l   = tid & 63;
    const int wk  = w >> 1;                     // K quarter (3 k-tiles)
    const int wn  = w & 1;                      // N half: tiles wn*4..wn*4+4
    const int nt0 = wn * 4;

    // zero-init LDS: A pad rows/chunks stay 0 forever; part2 zero for t=0
    for (int s = tid; s < 48*16*8; s += 512) { sAh[s] = 0; sAl[s] = 0; }
    for (int s = tid; s < 4*144*9; s += 512) (&part2[0][0][0])[s] = 0.f;

    // preload static B fragments: 5 tiles x 3 k-tiles x 2 planes = 120 VGPR
    bhalf8 bB[5][3][2];
    #pragma unroll
    for (int ti = 0; ti < 5; ++ti)
        #pragma unroll
        for (int kti = 0; kti < 3; ++kti)
            #pragma unroll
            for (int p = 0; p < 2; ++p)
                bB[ti][kti][p] = *reinterpret_cast<const bhalf8*>(
                    Wq2 + ((((size_t)(us*9 + nt0 + ti)*12 + (wk*3 + kti))*2 + p)*64 + l)*8);

    // gate-phase constants (one item per thread, tid < 368)
    const bool gact = tid < ROWS*NU;
    const int u1 = tid % NU, r1 = tid / NU;
    const int ug1 = us*NU + u1;
    float bh1r = 0.f, bh1z = 0.f, bh1n = 0.f;
    if (gact) { bh1r = bh[ug1]; bh1z = bh[H_+ug1]; bh1n = bh[2*H_+ug1]; }

    // staging geometry: wave w stages slice w = contiguous 184 u64 block at
    // u64 offset 184*w within the bg's 2944-word step block.
    // u64 index pi: u = 46w + (pi>>2), rows 2*(pi&3), 2*(pi&3)+1.
    int aoff2[3]; bool sact[3];
    #pragma unroll
    for (int ii = 0; ii < 3; ++ii) {
        const int pi = l + ii*64;
        sact[ii] = pi < 184;
        const int pc = sact[ii] ? pi : 0;
        const int u = NU*w + (pc >> 2), r2 = pc & 3;
        aoff2[ii] = ((u >> 3)*16 + 2*r2)*8 + (u & 7);
    }

    // per-lane A-frag LDS byte offset within a k-tile block (1024 B / k-tile)
    const int aoffb = (l >> 4)*256 + (l & 15)*16;

    __syncthreads();

    for (int t = 0; t < T_; ++t) {
        unsigned int* hout = h2 + ((size_t)t*32 + bg)*2944;   // [u][r] dense

        // prefetch gate operands (independent of h; hides under poll)
        float xg10 = 0.f, xg11 = 0.f, xg12 = 0.f;
        if (gact) {
            const float* xr1 = xproj + ((size_t)(b0 + r1)*T_ + t)*G3_;
            xg10 = xr1[ug1]; xg11 = xr1[H_+ug1]; xg12 = xr1[2*H_+ug1];
        }

        if (t > 0) {
            // poll-load slice w of h(t-1): data words ARE the flags.
            // Initial coalesced read of all 184 u64, then retry ONLY
            // stragglers (exec-masked) until no lane sees the sentinel.
            const unsigned long long* hin64 =
                reinterpret_cast<const unsigned long long*>(
                    h2 + ((size_t)(t - 1)*32 + bg)*2944) + 184*w;
            unsigned long long v[3];
            bool need[3];
            #pragma unroll
            for (int ii = 0; ii < 3; ++ii) {
                need[ii] = sact[ii];
                v[ii] = 0ull;
                if (need[ii]) v[ii] = bload_u2(hin64 + l + ii*64);
            }
            for (;;) {
                unsigned bad = 0u;
                #pragma unroll
                for (int ii = 0; ii < 3; ++ii) {
                    if (need[ii]) {
                        const bool inv = ((unsigned)v[ii] == SENT) ||
                                         ((unsigned)(v[ii] >> 32) == SENT);
                        need[ii] = inv;
                        if (inv) bad = 1u;
                    }
                }
                if (!__any(bad != 0u)) break;
                #pragma unroll
                for (int ii = 0; ii < 3; ++ii)
                    if (need[ii]) v[ii] = bload_u2(hin64 + l + ii*64);
            }
            #pragma unroll
            for (int ii = 0; ii < 3; ++ii) {
                if (sact[ii]) {
                    const unsigned int v0 = (unsigned int)v[ii];
                    const unsigned int v1 = (unsigned int)(v[ii] >> 32);
                    const int a = aoff2[ii];
                    sAh[a]     = (unsigned short)(v0 & 0xffffu);
                    sAl[a]     = (unsigned short)(v0 >> 16);
                    sAh[a + 8] = (unsigned short)(v1 & 0xffffu);
                    sAl[a + 8] = (unsigned short)(v1 >> 16);
                }
            }
            barrier_lds();
            // MFMA: 3 k-tiles x 5 n-tiles x 3 split terms = 45 MFMAs/wave
            f32x4 acc[5];
            #pragma unroll
            for (int ti = 0; ti < 5; ++ti) acc[ti] = f32x4{0.f,0.f,0.f,0.f};
            #pragma unroll
            for (int kti = 0; kti < 3; ++kti) {
                const int kt = wk*3 + kti;
                const bhalf8 fh = *reinterpret_cast<const bhalf8*>((const char*)sAh + kt*1024 + aoffb);
                const bhalf8 fl = *reinterpret_cast<const bhalf8*>((const char*)sAl + kt*1024 + aoffb);
                #pragma unroll
                for (int ti = 0; ti < 5; ++ti) {
                    acc[ti] = __builtin_amdgcn_mfma_f32_16x16x32_bf16(fh, bB[ti][kti][0], acc[ti], 0, 0, 0);
                    acc[ti] = __builtin_amdgcn_mfma_f32_16x16x32_bf16(fh, bB[ti][kti][1], acc[ti], 0, 0, 0);
                    acc[ti] = __builtin_amdgcn_mfma_f32_16x16x32_bf16(fl, bB[ti][kti][0], acc[ti], 0, 0, 0);
                }
            }
            // C frags -> per-wk partials (padded, conflict-free).
            // C layout: col=lane&15, row=(lane>>4)*4+reg; rows 0..7 in lanes 0..31.
            if (l < 32) {
                #pragma unroll
                for (int ti = 0; ti < 5; ++ti) {
                    const int col = (nt0 + ti)*16 + (l & 15);
                    float* pp = &part2[wk][col][(l >> 4)*4];
                    pp[0] = acc[ti][0]; pp[1] = acc[ti][1];
                    pp[2] = acc[ti][2]; pp[3] = acc[ti][3];
                }
            }
        }
        barrier_lds();

        // fused gates: one (unit,row) per thread
        if (gact) {
            float s0 = 0.f, s1 = 0.f, s2 = 0.f;
            #pragma unroll
            for (int q2 = 0; q2 < 4; ++q2) {
                s0 += part2[q2][u1][r1];
                s1 += part2[q2][NU + u1][r1];
                s2 += part2[q2][2*NU + u1][r1];
            }
            const float rg = 1.f/(1.f + expf(-(xg10 + s0 + bh1r)));
            const float zg = 1.f/(1.f + expf(-(xg11 + s1 + bh1z)));
            const float ng = tanhf(xg12 + rg*(s2 + bh1n));
            float hp = 0.f;
            if (t > 0) {
                const int a = ((ug1 >> 3)*16 + r1)*8 + (ug1 & 7);
                hp = bf2f(sAh[a]) + bf2f(sAl[a]);
            }
            const float hn = (1.f - zg)*ng + zg*hp;
            const unsigned short hi = f2bf(hn);
            const unsigned short lo = f2bf(hn - bf2f(hi));
            bstore_u(hout + ug1*8 + r1, (unsigned)hi | ((unsigned)lo << 16));
        }
        // LDS WAR only (gates' sAh/part2 reads vs next step's writes);
        // h stores intentionally NOT drained — words self-validate.
        barrier_lds();
    }
}

// ---------------------------------------------------------------------------
// K3: heads on temporal2 [t][bg][u][r] packed bf16 hi|lo; h = hi + lo.
// ---------------------------------------------------------------------------
__global__ __launch_bounds__(256) void k_heads2(const unsigned int* __restrict__ temporal2,
                                                const float* __restrict__ Wcat,
                                                const float* __restrict__ bc,
                                                const float* __restrict__ bf,
                                                float* __restrict__ cs,
                                                float* __restrict__ fine_out) {
    const int t = blockIdx.x;       // 0..95
    const int b = threadIdx.x;      // 0..255
    const unsigned int* tb = temporal2 + (size_t)t*HB_ + (b >> 3)*2944 + (b & 7);
    float acc[31];
    #pragma unroll
    for (int c = 0; c < 31; ++c) acc[c] = 0.f;
    for (int u = 0; u < H_; ++u) {
        const unsigned int v = tb[(size_t)u*8];
        const float x = bf2f((unsigned short)(v & 0xffffu)) + bf2f((unsigned short)(v >> 16));
        const float* wrow = Wcat + u*32;
        #pragma unroll
        for (int c = 0; c < 31; ++c) acc[c] = fmaf(x, wrow[c], acc[c]);
    }
    const float l0 = acc[0] + bc[0], l1 = acc[1] + bc[1];
    const float m  = fmaxf(l0, l1);
    const float e0 = expf(l0 - m), e1 = expf(l1 - m);
    const float inv = 1.f/(e0 + e1);
    cs[((size_t)b*T_ + t)*2]     = e0*inv;
    cs[((size_t)b*T_ + t)*2 + 1] = e1*inv;
    #pragma unroll
    for (int c = 2; c < 31; ++c) {
        fine_out[((size_t)b*T_ + t)*NC_ + (c-2)] = 1.f/(1.f + expf(-(acc[c] + bf[c-2])));
    }
}

// ---------------------------------------------------------------------------
// K4: NMS + argmax
// ---------------------------------------------------------------------------
__global__ __launch_bounds__(256) void k_nms(const float* __restrict__ cs,
                                             float* __restrict__ out_dec,
                                             float* __restrict__ out_nms) {
    const int idx = blockIdx.x*256 + threadIdx.x;   // < 24576
    const int t = idx % T_;
    const float bg = cs[idx*2], s1 = cs[idx*2+1];
    float wmin = bg;
    #pragma unroll
    for (int dt = -2; dt <= 2; ++dt) {
        const int tt = t + dt;
        if (dt != 0 && tt >= 0 && tt < T_) wmin = fminf(wmin, cs[(idx + dt)*2]);
    }
    const bool keep = (bg <= wmin);
    out_dec[idx]     = (keep && (s1 > bg)) ? 1.f : 0.f;
    out_nms[idx*2]   = keep ? bg : 0.f;
    out_nms[idx*2+1] = keep ? s1 : 0.f;
}

// ---------------------------------------------------------------------------
extern "C" void kernel_launch(void* const* d_in, const int* in_sizes, int n_in,
                              void* d_out, int out_size, void* d_ws, size_t ws_size,
                              hipStream_t stream) {
    const float* features = (const float*)d_in[0];
    const float* Wi = (const float*)d_in[2];
    const float* Wh = (const float*)d_in[3];
    const float* bi = (const float*)d_in[4];
    const float* bh = (const float*)d_in[5];
    const float* Wc = (const float*)d_in[6];
    const float* bc = (const float*)d_in[7];
    const float* Wf = (const float*)d_in[8];
    const float* bf = (const float*)d_in[9];

    float* out = (float*)d_out;
    float* out_dec  = out;                 // (B,T)     24576
    float* out_nms  = out + BT_;           // (B,T,2)   49152
    float* out_fine = out + BT_ + 2*BT_;   // (B,T,29)  712704

    // workspace: xproj f32 | Wq2 u16 frags | temporal2 u32
    float* xproj = (float*)d_ws;
    unsigned short* Wq2 = (unsigned short*)(xproj + (size_t)BT_*G3_);
    unsigned int* temporal2 = (unsigned int*)((char*)Wq2 + (size_t)WQ2_U16*2);
    float* Wcat = xproj;                   // xproj dead after GRU
    float* cs   = xproj + 12288;

    // phase-1 overlays (dead once consumers below run, stream-ordered):
    //   Bh/Bl (847,872 u16) fits inside Wq2 region (884,736 u16)
    //   Ah/Al (36,175,872 B) == temporal2 region exactly
    unsigned short* Bh16 = (unsigned short*)Wq2;
    unsigned short* Bl16 = Bh16 + (size_t)WQCOLS*F_;
    unsigned short* Ah16 = (unsigned short*)temporal2;
    unsigned short* Al16 = Ah16 + (size_t)BT_*F_;

    k_split_a<<<8832, 256, 0, stream>>>(features, Ah16, Al16);
    k_split_b<<<1656, 256, 0, stream>>>(Wi, Bh16, Bl16);
    k_xproj_mfma<<<dim3(9, 192), 256, 0, stream>>>(Ah16, Al16, Bh16, Bl16, bi, xproj);
    k_prep_wq2<<<432, 256, 0, stream>>>(Wh, Wq2);        // overwrites Bh/Bl (dead)
    k_fill_sent<<<8832, 256, 0, stream>>>(temporal2);    // overwrites Ah/Al (dead); re-poison
    k_gru_all<<<256, 512, 0, stream>>>(xproj, Wq2, bh, temporal2);
    k_prep_wcat<<<46, 256, 0, stream>>>(Wc, Wf, Wcat);
    k_heads2<<<96, 256, 0, stream>>>(temporal2, Wcat, bc, bf, cs, out_fine);
    k_nms<<<96, 256, 0, stream>>>(cs, out_dec, out_nms);
}